// Round 4
// baseline (28113.052 us; speedup 1.0000x reference)
//
#include <hip/hip_runtime.h>
#include <math.h>

// Problem constants
#define BB 32
#define CC 512
#define SS 256      // kv tokens
#define DD 2048     // d_model
#define DIN 512
#define NH 8
#define DHD 64
#define TT 50
#define MM 25
#define HHID 16
#define NSA 512
#define NSO 512
#define NOUT 1000

#define NBLK 256    // persistent grid size (1 block/CU, all resident)
#define BLKT 1024   // 16 waves/CU for latency hiding

// Dynamic LDS layout (floats): K [64][256] | V [256][64] | scratch 5152
#define KV_FLOATS 16384
#define SCRATCH_OFF (2 * KV_FLOATS)
#define SMEM_FLOATS (SCRATCH_OFF + 5152)   // 151,680 bytes

// ---------------------------------------------------------------------------
// Coherent (cross-XCD) access helpers: sc0/sc1 ops that bypass the
// non-coherent per-XCD L2 and complete at the MALL. Used ONLY for
// cross-block-communicated tensors; weights stay normal cached loads.
// ---------------------------------------------------------------------------
__device__ __forceinline__ float cld(const float* p) {
    return __hip_atomic_load(p, __ATOMIC_RELAXED, __HIP_MEMORY_SCOPE_AGENT);
}
__device__ __forceinline__ void cst(float* p, float v) {
    __hip_atomic_store(p, v, __ATOMIC_RELAXED, __HIP_MEMORY_SCOPE_AGENT);
}

// ---------------------------------------------------------------------------
// Init: barrier counter, decays, sync states, act0, trace0
// ---------------------------------------------------------------------------
__global__ void init_kernel(const float* __restrict__ dec_a, const float* __restrict__ dec_o,
                            const float* __restrict__ start_act, const float* __restrict__ start_trace,
                            const int* __restrict__ idx_lo, const int* __restrict__ idx_ro,
                            unsigned* __restrict__ bar,
                            float* __restrict__ r_a, float* __restrict__ r_o,
                            float* __restrict__ a_a, float* __restrict__ b_a,
                            float* __restrict__ a_o, float* __restrict__ b_o,
                            float* __restrict__ act, float* __restrict__ trace)
{
    int i = blockIdx.x * 256 + threadIdx.x;
    if (i < 16) bar[i] = 0u;
    if (i < 512) {
        r_a[i] = expf(-fminf(fmaxf(dec_a[i], 0.f), 15.f));
        r_o[i] = expf(-fminf(fmaxf(dec_o[i], 0.f), 15.f));
    }
    if (i < BB * NSA) {
        a_a[i] = 0.f; b_a[i] = 0.f;
        int j = i & 511;
        a_o[i] = start_act[idx_lo[j]] * start_act[idx_ro[j]];
        b_o[i] = 1.f;
    }
    if (i < BB * DD) act[i] = start_act[i & (DD - 1)];
    if (i < BB * MM * DD) {
        int rem = i % (MM * DD);
        int m = rem / DD, d = rem % DD;
        trace[i] = start_trace[d * MM + m];   // start_trace is (D,M)
    }
}

// ---------------------------------------------------------------------------
// Generic 64x64 tiled GEMM (precompute only).
// ---------------------------------------------------------------------------
template<int AMODE, int SMODE>
__global__ void gemm64(const float* __restrict__ A, const float* __restrict__ Bm,
                       const float* __restrict__ bias, float* __restrict__ Cm,
                       int Mdim, int Ndim, int Kdim)
{
    __shared__ float As[16 * 65];
    __shared__ float Bs[16 * 64];
    int row0 = blockIdx.x * 64;
    int col0 = blockIdx.y * 64;
    int t = threadIdx.x;
    int tx = t & 15, ty = t >> 4;
    float acc[4][4] = {};
    for (int k0 = 0; k0 < Kdim; k0 += 16) {
        if (AMODE == 0) {
            for (int i = t; i < 1024; i += 256) {
                int kk = i & 15, r = i >> 4;
                As[kk * 65 + r] = A[(size_t)(row0 + r) * Kdim + k0 + kk];
            }
        } else {
            int b = row0 / SS, s0 = row0 % SS;
            for (int i = t; i < 1024; i += 256) {
                int r = i & 63, kk = i >> 6;
                As[kk * 65 + r] = A[((size_t)b * CC + k0 + kk) * SS + s0 + r];
            }
        }
        for (int i = t; i < 1024; i += 256) {
            int c = i & 63, kk = i >> 6;
            Bs[kk * 64 + c] = Bm[(size_t)(k0 + kk) * Ndim + col0 + c];
        }
        __syncthreads();
        #pragma unroll
        for (int kk = 0; kk < 16; ++kk) {
            float a[4], bb[4];
            #pragma unroll
            for (int i = 0; i < 4; i++) a[i] = As[kk * 65 + ty * 4 + i];
            #pragma unroll
            for (int j = 0; j < 4; j++) bb[j] = Bs[kk * 64 + tx * 4 + j];
            #pragma unroll
            for (int i = 0; i < 4; i++)
                #pragma unroll
                for (int j = 0; j < 4; j++) acc[i][j] += a[i] * bb[j];
        }
        __syncthreads();
    }
    #pragma unroll
    for (int i = 0; i < 4; i++)
        #pragma unroll
        for (int j = 0; j < 4; j++) {
            int row = row0 + ty * 4 + i, col = col0 + tx * 4 + j;
            float v = acc[i][j] + (bias ? bias[col] : 0.f);
            if (SMODE == 0) {
                Cm[(size_t)row * Ndim + col] = v;
            } else if (SMODE == 1) {
                int b = row / SS, s = row % SS, h = col >> 6, dh = col & 63;
                Cm[(((size_t)b * NH + h) * DHD + dh) * SS + s] = v;
            } else {
                int b = row / SS, s = row % SS, h = col >> 6, dh = col & 63;
                Cm[(((size_t)b * NH + h) * SS + s) * DHD + dh] = v;
            }
        }
}

// LayerNorm over rows of 512 (in place)
__global__ void ln_rows(float* __restrict__ buf, const float* __restrict__ g,
                        const float* __restrict__ bta)
{
    int row = blockIdx.x, t = threadIdx.x;
    __shared__ float red[256];
    float v0 = buf[(size_t)row * 512 + t];
    float v1 = buf[(size_t)row * 512 + 256 + t];
    red[t] = v0 + v1; __syncthreads();
    for (int off = 128; off; off >>= 1) { if (t < off) red[t] += red[t + off]; __syncthreads(); }
    float mu = red[0] * (1.f / 512.f); __syncthreads();
    float d0 = v0 - mu, d1 = v1 - mu;
    red[t] = d0 * d0 + d1 * d1; __syncthreads();
    for (int off = 128; off; off >>= 1) { if (t < off) red[t] += red[t + off]; __syncthreads(); }
    float rstd = 1.f / sqrtf(red[0] * (1.f / 512.f) + 1e-5f);
    buf[(size_t)row * 512 + t]       = d0 * rstd * g[t] + bta[t];
    buf[(size_t)row * 512 + 256 + t] = d1 * rstd * g[t + 256] + bta[t + 256];
}

__global__ void bqq_kernel(const float* __restrict__ q_b, const float* __restrict__ Wq,
                           const float* __restrict__ bq, float* __restrict__ bqq)
{
    int c = blockIdx.x * 256 + threadIdx.x;
    if (c >= 512) return;
    float acc = bq[c];
    for (int k = 0; k < 512; k++) acc += q_b[k] * Wq[k * 512 + c];
    bqq[c] = acc;
}

__global__ void bias2_kernel(const float* __restrict__ bo, const float* __restrict__ syn_w,
                             const float* __restrict__ syn_b, float* __restrict__ bias2)
{
    int c = blockIdx.x * 256 + threadIdx.x;
    if (c >= 4096) return;
    float acc = syn_b[c];
    for (int k = 0; k < 512; k++) acc += bo[k] * syn_w[(size_t)k * 4096 + c];
    bias2[c] = acc;
}

// ---------------------------------------------------------------------------
// Fence-free grid barrier (no L2 flush/invalidate). Monotone counter.
// ---------------------------------------------------------------------------
__device__ __forceinline__ void gsync(unsigned* __restrict__ ctr, unsigned target)
{
    __threadfence_block();     // drain this wave's coherent stores (vmcnt(0))
    __syncthreads();
    if (threadIdx.x == 0) {
        __hip_atomic_fetch_add(ctr, 1u, __ATOMIC_RELAXED, __HIP_MEMORY_SCOPE_AGENT);
        while (__hip_atomic_load(ctr, __ATOMIC_RELAXED, __HIP_MEMORY_SCOPE_AGENT) < target)
            __builtin_amdgcn_s_sleep(4);
        asm volatile("" ::: "memory");
    }
    __syncthreads();
}

// ---------------------------------------------------------------------------
// Persistent tick kernel. 256 blocks x 1024 threads, 148 KB dynamic LDS.
// ---------------------------------------------------------------------------
struct TickArgs {
    const float* Wqq; const float* bqq;
    const float* khT; const float* vh;
    const float* W2;  const float* syn_w; const float* bias2;
    const float* g_syn; const float* bt_syn;
    const float* w1; const float* b1; const float* w2; const float* b2;
    const float* out_w; const float* out_b;
    const float* r_a; const float* r_o;
    const int* la; const int* ra; const int* lo; const int* ro;
    float* a_a; float* b_a;      // [2][BB*512] ping-pong
    float* a_o; float* b_o;      // [2][BB*512] ping-pong
    float* act; float* trace; float* obuf; float* upart; float* ppart;
    float* out; float* out_sync;
    unsigned* bar;
};

__global__ __launch_bounds__(BLKT) void tick_kernel(TickArgs A)
{
    extern __shared__ float smem[];
    float* kls = smem;                 // [64][256] khT for this (b,h)
    float* vls = smem + KV_FLOATS;     // [256][64] vh for this (b,h)
    float* scratch = smem + SCRATCH_OFF;
    const int blk = blockIdx.x;
    const int tid = threadIdx.x;
    unsigned nb = 0;

    // ---- one-time: pin this block's K/V tile in LDS for all 50 ticks ----
    {
        const float* kg = A.khT + (size_t)blk * KV_FLOATS;
        const float* vg = A.vh + (size_t)blk * KV_FLOATS;
        for (int i = tid; i < KV_FLOATS; i += BLKT) {
            kls[i] = kg[i];
            vls[i] = vg[i];
        }
        __syncthreads();
    }

    for (int t = 0; t < TT; ++t) {
        const int par = t & 1;

        // ============ P1: sync_a + qh slice + attention, block = (b,h) ======
        {
            int b = blk >> 3, h = blk & 7;
            float* sa  = scratch;           // 512
            float* qp  = scratch + 512;     // 1024
            float* qs  = scratch + 1536;    // 64
            float* ps  = scratch + 1600;    // 256
            float* red = scratch + 1856;    // 1024
            const float* aold = A.a_a + par * (BB * 512);
            const float* bold = A.b_a + par * (BB * 512);
            float* anew = A.a_a + (par ^ 1) * (BB * 512);
            float* bnew = A.b_a + (par ^ 1) * (BB * 512);
            const float* actb = A.act + b * DD;
            if (tid < 512) {
                int j = tid;
                float p = cld(&actb[A.la[j]]) * cld(&actb[A.ra[j]]);
                float r = A.r_a[j];
                float aa = r * cld(&aold[b * 512 + j]) + p;
                float bb = r * cld(&bold[b * 512 + j]) + 1.f;
                sa[j] = aa / sqrtf(bb);
                if (h == 0) { cst(&anew[b * 512 + j], aa); cst(&bnew[b * 512 + j], bb); }
            }
            __syncthreads();
            // qh slice: c = h*64 + cl, K split into 16 chunks of 32
            {
                int cl = tid & 63, q = tid >> 6;
                const float* wcol = A.Wqq + h * 64 + cl;
                float acc = 0.f;
                #pragma unroll 8
                for (int k = q * 32; k < q * 32 + 32; ++k)
                    acc += sa[k] * wcol[k * 512];
                qp[tid] = acc;
            }
            __syncthreads();
            if (tid < 64) {
                float s = A.bqq[h * 64 + tid];
                #pragma unroll
                for (int i = 0; i < 16; ++i) s += qp[tid + 64 * i];
                qs[tid] = s;
            }
            __syncthreads();
            // scores from LDS K (threads 0..255 = s)
            float sc = 0.f;
            if (tid < 256) {
                #pragma unroll 16
                for (int dh = 0; dh < 64; ++dh) sc += qs[dh] * kls[dh * 256 + tid];
                sc *= 0.125f;
            }
            red[tid] = (tid < 256) ? sc : -1e30f;
            __syncthreads();
            for (int off = 512; off; off >>= 1) { if (tid < off) red[tid] = fmaxf(red[tid], red[tid + off]); __syncthreads(); }
            float mx = red[0]; __syncthreads();
            float e = (tid < 256) ? expf(sc - mx) : 0.f;
            red[tid] = e; __syncthreads();
            for (int off = 512; off; off >>= 1) { if (tid < off) red[tid] += red[tid + off]; __syncthreads(); }
            float inv = 1.f / red[0];
            if (tid < 256) ps[tid] = e * inv;
            __syncthreads();
            // PV from LDS V: dh = tid&63, 16 chunks of 16 s
            {
                int dh = tid & 63, ch = tid >> 6;
                float acc = 0.f;
                #pragma unroll
                for (int s = ch * 16; s < ch * 16 + 16; ++s) acc += ps[s] * vls[s * 64 + dh];
                red[tid] = acc; __syncthreads();
                if (tid < 512) red[tid] += red[tid + 512]; __syncthreads();
                if (tid < 256) red[tid] += red[tid + 256]; __syncthreads();
                if (tid < 128) red[tid] += red[tid + 128]; __syncthreads();
                if (tid < 64) cst(&A.obuf[b * 512 + h * 64 + tid], red[tid] + red[tid + 64]);
            }
        }
        nb += NBLK; gsync(A.bar, nb);

        // ============ P2: synapse GEMM. block = (ks 0..15, colpair 0..15) ===
        // Stage A-tile (32 x 160) ONCE, compute 256 output cols with batched
        // float4 weight loads (8 in flight per wave).
        {
            int ks = blk >> 4;            // 0..15
            int npair = blk & 15;         // 0..15
            int k0 = ks * 160;
            float* As = scratch;          // 32*161
            __syncthreads();
            for (int i = tid; i < 32 * 160; i += BLKT) {
                int k = i % 160, r = i / 160;
                int kk = k0 + k;
                float v = (kk < 512) ? cld(&A.obuf[r * 512 + kk])
                                     : cld(&A.act[r * 2048 + (kk - 512)]);
                As[r * 161 + k] = v;
            }
            __syncthreads();
            int ct = tid & 63, rt = tid >> 6;   // 64 col-groups x 16 row-groups
            int c0 = npair * 256 + ct * 4;
            int r2 = rt * 2;
            float acc[2][4] = {};
            for (int k = 0; k < 160; k += 8) {
                float4 wreg[8];
                #pragma unroll
                for (int u = 0; u < 8; ++u) {
                    int kk = k0 + k + u;
                    const float* wr = (kk < 512 ? A.W2 : A.syn_w) + (size_t)kk * 4096 + c0;
                    wreg[u] = *(const float4*)wr;
                }
                #pragma unroll
                for (int u = 0; u < 8; ++u) {
                    float a0 = As[(r2 + 0) * 161 + k + u];
                    float a1 = As[(r2 + 1) * 161 + k + u];
                    acc[0][0] += a0 * wreg[u].x; acc[0][1] += a0 * wreg[u].y;
                    acc[0][2] += a0 * wreg[u].z; acc[0][3] += a0 * wreg[u].w;
                    acc[1][0] += a1 * wreg[u].x; acc[1][1] += a1 * wreg[u].y;
                    acc[1][2] += a1 * wreg[u].z; acc[1][3] += a1 * wreg[u].w;
                }
            }
            #pragma unroll
            for (int i = 0; i < 2; i++) {
                float* dst = A.upart + ((size_t)(ks * 32) + r2 + i) * 4096 + c0;
                cst(dst + 0, acc[i][0]); cst(dst + 1, acc[i][1]);
                cst(dst + 2, acc[i][2]); cst(dst + 3, acc[i][3]);
            }
        }
        nb += NBLK; gsync(A.bar, nb);

        // ============ P3: glu_ln (blk 0..31) ================================
        if (blk < 32) {
            int b = blk;
            float* red = scratch;   // 1024
            float vals[2];
            float loc = 0.f;
            #pragma unroll
            for (int ii = 0; ii < 2; ++ii) {
                int d = tid + ii * 1024;
                float ua[16], ub[16];
                #pragma unroll
                for (int ks = 0; ks < 16; ++ks) {
                    const float* rowp = A.upart + (size_t)(ks * 32 + b) * 4096;
                    ua[ks] = cld(&rowp[d]);
                    ub[ks] = cld(&rowp[d + 2048]);
                }
                float a = A.bias2[d], bb = A.bias2[d + 2048];
                #pragma unroll
                for (int ks = 0; ks < 16; ++ks) { a += ua[ks]; bb += ub[ks]; }
                float gl = a * (1.f / (1.f + expf(-bb)));
                vals[ii] = gl; loc += gl;
            }
            red[tid] = loc; __syncthreads();
            for (int off = 512; off; off >>= 1) { if (tid < off) red[tid] += red[tid + off]; __syncthreads(); }
            float mu = red[0] * (1.f / 2048.f); __syncthreads();
            float l2 = 0.f;
            #pragma unroll
            for (int ii = 0; ii < 2; ++ii) { float dq = vals[ii] - mu; l2 += dq * dq; }
            red[tid] = l2; __syncthreads();
            for (int off = 512; off; off >>= 1) { if (tid < off) red[tid] += red[tid + off]; __syncthreads(); }
            float rstd = 1.f / sqrtf(red[0] * (1.f / 2048.f) + 1e-5f);
            float* trow = A.trace + ((size_t)b * MM + (t % MM)) * DD;
            #pragma unroll
            for (int ii = 0; ii < 2; ++ii) {
                int d = tid + ii * 1024;
                cst(&trow[d], (vals[ii] - mu) * rstd * A.g_syn[d] + A.bt_syn[d]);
            }
        }
        nb += NBLK; gsync(A.bar, nb);

        // ============ P4: per-neuron MLP -> act (all blocks, tid<256) =======
        if (tid < 256) {
            int i = blk * 256 + tid;
            int b = i >> 11, d = i & 2047;
            const float* tr = A.trace + (size_t)b * MM * DD;
            float tv[25];
            #pragma unroll
            for (int m = 0; m < 25; m++) {
                int mph = (t + 1 + m) % 25;     // logical->physical circular map
                tv[m] = cld(&tr[mph * DD + d]);
            }
            float hp[32];
            #pragma unroll
            for (int h = 0; h < 32; h++) hp[h] = A.b1[d * 32 + h];
            for (int m = 0; m < 25; m++) {
                float tvm = tv[m];
                #pragma unroll
                for (int h = 0; h < 32; h++) hp[h] += tvm * A.w1[((size_t)m * 32 + h) * DD + d];
            }
            float o0 = A.b2[d * 2], o1 = A.b2[d * 2 + 1];
            #pragma unroll
            for (int h = 0; h < 16; h++) {
                float hv = hp[h] * (1.f / (1.f + expf(-hp[h + 16])));
                o0 += hv * A.w2[((size_t)h * 2) * DD + d];
                o1 += hv * A.w2[((size_t)h * 2 + 1) * DD + d];
            }
            cst(&A.act[i], o0 * (1.f / (1.f + expf(-o1))));
        }
        nb += NBLK; gsync(A.bar, nb);

        // ============ P5: sync_o fused into pred GEMM (blk 0..63) ===========
        if (blk < 64) {
            int ks = blk >> 3, ctile = blk & 7;
            int k0 = ks * 64;
            const float* aold = A.a_o + par * (BB * 512);
            const float* bold = A.b_o + par * (BB * 512);
            float* anew = A.a_o + (par ^ 1) * (BB * 512);
            float* bnew = A.b_o + (par ^ 1) * (BB * 512);
            float* As = scratch;   // 32*65
            #pragma unroll
            for (int q = 0; q < 2; ++q) {
                int idx = tid + q * 1024;         // 0..2047
                int r = idx >> 6, jl = idx & 63;
                int j = k0 + jl;
                const float* actb = A.act + r * DD;
                float p = cld(&actb[A.lo[j]]) * cld(&actb[A.ro[j]]);
                float rr = A.r_o[j];
                float aa = rr * cld(&aold[r * 512 + j]) + p;
                float bb = rr * cld(&bold[r * 512 + j]) + 1.f;
                float s = aa / sqrtf(bb);
                As[r * 65 + jl] = s;
                if (ctile == 0) {
                    cst(&anew[r * 512 + j], aa);
                    cst(&bnew[r * 512 + j], bb);
                    if (t == TT - 1) A.out_sync[r * 512 + j] = s;
                }
            }
            __syncthreads();
            int ct = tid & 31, rt = tid >> 5;   // 32 cols x 32 rows
            int cc = ctile * 128 + ct * 4;
            if (cc < 1000) {
                float acc[4] = {};
                for (int k = 0; k < 64; k += 8) {
                    float4 wreg[8];
                    #pragma unroll
                    for (int u = 0; u < 8; ++u)
                        wreg[u] = *(const float4*)(A.out_w + (size_t)(k0 + k + u) * 1000 + cc);
                    #pragma unroll
                    for (int u = 0; u < 8; ++u) {
                        float a0 = As[rt * 65 + k + u];
                        acc[0] += a0 * wreg[u].x; acc[1] += a0 * wreg[u].y;
                        acc[2] += a0 * wreg[u].z; acc[3] += a0 * wreg[u].w;
                    }
                }
                float* dst = A.ppart + (size_t)(ks * 32 + rt) * 1000 + cc;
                cst(dst + 0, acc[0]); cst(dst + 1, acc[1]);
                cst(dst + 2, acc[2]); cst(dst + 3, acc[3]);
            }
        }
        nb += NBLK; gsync(A.bar, nb);

        // ============ P6: cert for tick t (blk 224..255), no trailing sync ==
        // Overlaps next tick's P1; its input (ppart) is rewritten 4 barriers
        // later, so this is race-free.
        if (blk >= 224) {
            int b = blk - 224;
            float* red = scratch;   // 1024
            float v = -1e30f;
            if (tid < 1000) {
                float pp[8];
                #pragma unroll
                for (int ks = 0; ks < 8; ++ks)
                    pp[ks] = cld(&A.ppart[(size_t)(ks * 32 + b) * 1000 + tid]);
                v = A.out_b[tid];
                #pragma unroll
                for (int ks = 0; ks < 8; ++ks) v += pp[ks];
                A.out[(size_t)b * NOUT * TT + (size_t)tid * TT + t] = v;
            }
            red[tid] = v; __syncthreads();
            for (int off = 512; off; off >>= 1) { if (tid < off) red[tid] = fmaxf(red[tid], red[tid + off]); __syncthreads(); }
            float mx = red[0]; __syncthreads();
            float s1 = 0.f, s2 = 0.f;
            if (tid < 1000) { float xx = v - mx; float e = expf(xx); s1 = e; s2 = e * xx; }
            red[tid] = s1; __syncthreads();
            for (int off = 512; off; off >>= 1) { if (tid < off) red[tid] += red[tid + off]; __syncthreads(); }
            s1 = red[0]; __syncthreads();
            red[tid] = s2; __syncthreads();
            for (int off = 512; off; off >>= 1) { if (tid < off) red[tid] += red[tid + off]; __syncthreads(); }
            s2 = red[0];
            if (tid == 0) {
                float ne = -(s2 / s1 - logf(s1)) * (1.f / logf(1000.f));
                size_t base = (size_t)BB * NOUT * TT + (size_t)b * 2 * TT + t;
                A.out[base] = ne;
                A.out[base + TT] = 1.f - ne;
            }
            __syncthreads();
        }
    }
}

// ---------------------------------------------------------------------------
extern "C" void kernel_launch(void* const* d_in, const int* in_sizes, int n_in,
                              void* d_out, int out_size, void* d_ws, size_t ws_size,
                              hipStream_t stream)
{
    const float* x        = (const float*)d_in[0];
    const float* kv_w     = (const float*)d_in[1];
    const float* kv_b     = (const float*)d_in[2];
    const float* ln_kv_g  = (const float*)d_in[3];
    const float* ln_kv_b  = (const float*)d_in[4];
    const float* q_w      = (const float*)d_in[5];
    const float* q_b      = (const float*)d_in[6];
    const float* Wq       = (const float*)d_in[7];
    const float* bq       = (const float*)d_in[8];
    const float* Wk       = (const float*)d_in[9];
    const float* bk       = (const float*)d_in[10];
    const float* Wv       = (const float*)d_in[11];
    const float* bv       = (const float*)d_in[12];
    const float* Wo       = (const float*)d_in[13];
    const float* bo       = (const float*)d_in[14];
    const float* syn_w    = (const float*)d_in[15];
    const float* syn_b    = (const float*)d_in[16];
    const float* ln_syn_g = (const float*)d_in[17];
    const float* ln_syn_b = (const float*)d_in[18];
    const float* nlm_w1   = (const float*)d_in[19];
    const float* nlm_b1   = (const float*)d_in[20];
    const float* nlm_w2   = (const float*)d_in[21];
    const float* nlm_b2   = (const float*)d_in[22];
    const float* out_w    = (const float*)d_in[23];
    const float* out_b    = (const float*)d_in[24];
    const float* dec_a    = (const float*)d_in[25];
    const float* dec_o    = (const float*)d_in[26];
    const float* start_tr = (const float*)d_in[27];
    const float* start_ac = (const float*)d_in[28];
    const int*   idx_la   = (const int*)d_in[29];
    const int*   idx_ra   = (const int*)d_in[30];
    const int*   idx_lo   = (const int*)d_in[31];
    const int*   idx_ro   = (const int*)d_in[32];
    float* out = (float*)d_out;

    // workspace carve: barrier (256B) then floats
    unsigned* bar = (unsigned*)d_ws;
    float* w = (float*)d_ws + 64;
    float* kvbuf = w;            w += (size_t)8192 * 512;
    float* khT   = w;            w += (size_t)8192 * 512;
    float* vhb   = w;            w += (size_t)8192 * 512;
    float* Wqq   = w;            w += (size_t)512 * 512;
    float* bqq   = w;            w += 512;
    float* W2    = w;            w += (size_t)512 * 4096;
    float* bias2 = w;            w += 4096;
    float* r_a   = w;            w += 512;
    float* r_o   = w;            w += 512;
    float* a_a   = w;            w += 2 * BB * NSA;           // ping-pong
    float* b_a   = w;            w += 2 * BB * NSA;
    float* a_o   = w;            w += 2 * BB * NSO;
    float* b_o   = w;            w += 2 * BB * NSO;
    float* act   = w;            w += BB * DD;
    float* trace = w;            w += (size_t)BB * MM * DD;
    float* obuf  = w;            w += BB * DIN;
    float* upart = w;            w += (size_t)16 * 32 * 4096;
    float* ppart = w;            w += (size_t)8 * 32 * 1000;

    // ---- precompute ----
    init_kernel<<<6400, 256, 0, stream>>>(dec_a, dec_o, start_ac, start_tr, idx_lo, idx_ro,
                                          bar, r_a, r_o, a_a, b_a, a_o, b_o, act, trace);
    gemm64<1, 0><<<dim3(128, 8), 256, 0, stream>>>(x, kv_w, kv_b, kvbuf, 8192, 512, 512);
    ln_rows<<<8192, 256, 0, stream>>>(kvbuf, ln_kv_g, ln_kv_b);
    gemm64<0, 1><<<dim3(128, 8), 256, 0, stream>>>(kvbuf, Wk, bk, khT, 8192, 512, 512);
    gemm64<0, 2><<<dim3(128, 8), 256, 0, stream>>>(kvbuf, Wv, bv, vhb, 8192, 512, 512);
    gemm64<0, 0><<<dim3(8, 8), 256, 0, stream>>>(q_w, Wq, nullptr, Wqq, 512, 512, 512);
    bqq_kernel<<<2, 256, 0, stream>>>(q_b, Wq, bq, bqq);
    gemm64<0, 0><<<dim3(8, 64), 256, 0, stream>>>(Wo, syn_w, nullptr, W2, 512, 4096, 512);
    bias2_kernel<<<16, 256, 0, stream>>>(bo, syn_w, syn_b, bias2);

    float* out_sync = out + (size_t)BB * NOUT * TT + (size_t)BB * 2 * TT;

    TickArgs ta;
    ta.Wqq = Wqq; ta.bqq = bqq;
    ta.khT = khT; ta.vh = vhb;
    ta.W2 = W2; ta.syn_w = syn_w; ta.bias2 = bias2;
    ta.g_syn = ln_syn_g; ta.bt_syn = ln_syn_b;
    ta.w1 = nlm_w1; ta.b1 = nlm_b1; ta.w2 = nlm_w2; ta.b2 = nlm_b2;
    ta.out_w = out_w; ta.out_b = out_b;
    ta.r_a = r_a; ta.r_o = r_o;
    ta.la = idx_la; ta.ra = idx_ra; ta.lo = idx_lo; ta.ro = idx_ro;
    ta.a_a = a_a; ta.b_a = b_a; ta.a_o = a_o; ta.b_o = b_o;
    ta.act = act; ta.trace = trace; ta.obuf = obuf; ta.upart = upart; ta.ppart = ppart;
    ta.out = out; ta.out_sync = out_sync;
    ta.bar = bar;

    // 148 KB dynamic LDS (>64 KB needs explicit opt-in)
    static int lds_attr_set = 0;
    if (!lds_attr_set) {
        hipFuncSetAttribute(reinterpret_cast<const void*>(tick_kernel),
                            hipFuncAttributeMaxDynamicSharedMemorySize,
                            SMEM_FLOATS * 4);
        lds_attr_set = 1;
    }
    tick_kernel<<<NBLK, BLKT, SMEM_FLOATS * 4, stream>>>(ta);
}

// Round 5
// 9267.892 us; speedup vs baseline: 3.0334x; 3.0334x over previous
//
#include <hip/hip_runtime.h>
#include <math.h>

// Problem constants
#define BB 32
#define CC 512
#define SS 256      // kv tokens
#define DD 2048     // d_model
#define DIN 512
#define NH 8
#define DHD 64
#define TT 50
#define MM 25
#define HHID 16
#define NSA 512
#define NSO 512
#define NOUT 1000

// ---------------------------------------------------------------------------
// Init: decays, sync states (ping-pong buffer 0), act0, trace0
// ---------------------------------------------------------------------------
__global__ void init_kernel(const float* __restrict__ dec_a, const float* __restrict__ dec_o,
                            const float* __restrict__ start_act, const float* __restrict__ start_trace,
                            const int* __restrict__ idx_lo, const int* __restrict__ idx_ro,
                            float* __restrict__ r_a, float* __restrict__ r_o,
                            float* __restrict__ a_a, float* __restrict__ b_a,
                            float* __restrict__ a_o, float* __restrict__ b_o,
                            float* __restrict__ act, float* __restrict__ trace)
{
    int i = blockIdx.x * 256 + threadIdx.x;
    if (i < 512) {
        r_a[i] = expf(-fminf(fmaxf(dec_a[i], 0.f), 15.f));
        r_o[i] = expf(-fminf(fmaxf(dec_o[i], 0.f), 15.f));
    }
    if (i < BB * NSA) {
        a_a[i] = 0.f; b_a[i] = 0.f;
        int j = i & 511;
        a_o[i] = start_act[idx_lo[j]] * start_act[idx_ro[j]];
        b_o[i] = 1.f;
    }
    if (i < BB * DD) act[i] = start_act[i & (DD - 1)];
    if (i < BB * MM * DD) {
        int rem = i % (MM * DD);
        int m = rem / DD, d = rem % DD;
        trace[i] = start_trace[d * MM + m];   // start_trace is (D,M)
    }
}

// ---------------------------------------------------------------------------
// Generic 64x64 tiled GEMM (precompute only). AMODE 0: row-major A[row*K+k].
// AMODE 1: A is x (B,C,S) with row=(b,s), k=c. SMODE 0: plain row-major +
// bias. SMODE 1: store khT (B,H,DH,S). SMODE 2: store vh (B,H,S,DH).
// ---------------------------------------------------------------------------
template<int AMODE, int SMODE>
__global__ void gemm64(const float* __restrict__ A, const float* __restrict__ Bm,
                       const float* __restrict__ bias, float* __restrict__ Cm,
                       int Mdim, int Ndim, int Kdim)
{
    __shared__ float As[16 * 65];
    __shared__ float Bs[16 * 64];
    int row0 = blockIdx.x * 64;
    int col0 = blockIdx.y * 64;
    int t = threadIdx.x;
    int tx = t & 15, ty = t >> 4;
    float acc[4][4] = {};
    for (int k0 = 0; k0 < Kdim; k0 += 16) {
        if (AMODE == 0) {
            for (int i = t; i < 1024; i += 256) {
                int kk = i & 15, r = i >> 4;
                As[kk * 65 + r] = A[(size_t)(row0 + r) * Kdim + k0 + kk];
            }
        } else {
            int b = row0 / SS, s0 = row0 % SS;
            for (int i = t; i < 1024; i += 256) {
                int r = i & 63, kk = i >> 6;
                As[kk * 65 + r] = A[((size_t)b * CC + k0 + kk) * SS + s0 + r];
            }
        }
        for (int i = t; i < 1024; i += 256) {
            int c = i & 63, kk = i >> 6;
            Bs[kk * 64 + c] = Bm[(size_t)(k0 + kk) * Ndim + col0 + c];
        }
        __syncthreads();
        #pragma unroll
        for (int kk = 0; kk < 16; ++kk) {
            float a[4], bb[4];
            #pragma unroll
            for (int i = 0; i < 4; i++) a[i] = As[kk * 65 + ty * 4 + i];
            #pragma unroll
            for (int j = 0; j < 4; j++) bb[j] = Bs[kk * 64 + tx * 4 + j];
            #pragma unroll
            for (int i = 0; i < 4; i++)
                #pragma unroll
                for (int j = 0; j < 4; j++) acc[i][j] += a[i] * bb[j];
        }
        __syncthreads();
    }
    #pragma unroll
    for (int i = 0; i < 4; i++)
        #pragma unroll
        for (int j = 0; j < 4; j++) {
            int row = row0 + ty * 4 + i, col = col0 + tx * 4 + j;
            float v = acc[i][j] + (bias ? bias[col] : 0.f);
            if (SMODE == 0) {
                Cm[(size_t)row * Ndim + col] = v;
            } else if (SMODE == 1) {
                int b = row / SS, s = row % SS, h = col >> 6, dh = col & 63;
                Cm[(((size_t)b * NH + h) * DHD + dh) * SS + s] = v;
            } else {
                int b = row / SS, s = row % SS, h = col >> 6, dh = col & 63;
                Cm[(((size_t)b * NH + h) * SS + s) * DHD + dh] = v;
            }
        }
}

// LayerNorm over rows of 512 (in place)
__global__ void ln_rows(float* __restrict__ buf, const float* __restrict__ g,
                        const float* __restrict__ bta)
{
    int row = blockIdx.x, t = threadIdx.x;
    __shared__ float red[256];
    float v0 = buf[(size_t)row * 512 + t];
    float v1 = buf[(size_t)row * 512 + 256 + t];
    red[t] = v0 + v1; __syncthreads();
    for (int off = 128; off; off >>= 1) { if (t < off) red[t] += red[t + off]; __syncthreads(); }
    float mu = red[0] * (1.f / 512.f); __syncthreads();
    float d0 = v0 - mu, d1 = v1 - mu;
    red[t] = d0 * d0 + d1 * d1; __syncthreads();
    for (int off = 128; off; off >>= 1) { if (t < off) red[t] += red[t + off]; __syncthreads(); }
    float rstd = 1.f / sqrtf(red[0] * (1.f / 512.f) + 1e-5f);
    buf[(size_t)row * 512 + t]       = d0 * rstd * g[t] + bta[t];
    buf[(size_t)row * 512 + 256 + t] = d1 * rstd * g[t + 256] + bta[t + 256];
}

__global__ void bqq_kernel(const float* __restrict__ q_b, const float* __restrict__ Wq,
                           const float* __restrict__ bq, float* __restrict__ bqq)
{
    int c = blockIdx.x * 256 + threadIdx.x;
    if (c >= 512) return;
    float acc = bq[c];
    for (int k = 0; k < 512; k++) acc += q_b[k] * Wq[k * 512 + c];
    bqq[c] = acc;
}

__global__ void bias2_kernel(const float* __restrict__ bo, const float* __restrict__ syn_w,
                             const float* __restrict__ syn_b, float* __restrict__ bias2)
{
    int c = blockIdx.x * 256 + threadIdx.x;
    if (c >= 4096) return;
    float acc = syn_b[c];
    for (int k = 0; k < 512; k++) acc += bo[k] * syn_w[(size_t)k * 4096 + c];
    bias2[c] = acc;
}

// ---------------------------------------------------------------------------
// K1: sync_a + q-projection slice + attention. Block = (b,h), 256 threads.
// Ping-pong a_a/b_a; only h==0 writes the new state.
// ---------------------------------------------------------------------------
__global__ __launch_bounds__(256) void k1_front(
    const float* __restrict__ act, const int* __restrict__ la, const int* __restrict__ ra,
    const float* __restrict__ r_a,
    const float* __restrict__ aold, const float* __restrict__ bold,
    float* __restrict__ anew, float* __restrict__ bnew,
    const float* __restrict__ Wqq, const float* __restrict__ bqq,
    const float* __restrict__ khT, const float* __restrict__ vh,
    float* __restrict__ obuf)
{
    __shared__ float sa[512];
    __shared__ float qp[256];
    __shared__ float qs[64];
    __shared__ float ps[256];
    __shared__ float red[256];
    int bh = blockIdx.x, b = bh >> 3, h = bh & 7;
    int tid = threadIdx.x;
    const float* actb = act + b * DD;
    for (int j = tid; j < 512; j += 256) {
        float p = actb[la[j]] * actb[ra[j]];
        float r = r_a[j];
        float aa = r * aold[b * 512 + j] + p;
        float bb = r * bold[b * 512 + j] + 1.f;
        sa[j] = aa / sqrtf(bb);
        if (h == 0) { anew[b * 512 + j] = aa; bnew[b * 512 + j] = bb; }
    }
    __syncthreads();
    // qh slice for this head: c = h*64 + cl, K split into 4 chunks of 128
    {
        int cl = tid & 63, q = tid >> 6;
        const float* wcol = Wqq + h * 64 + cl;
        float acc = 0.f;
        #pragma unroll 8
        for (int k = q * 128; k < q * 128 + 128; ++k)
            acc += sa[k] * wcol[k * 512];
        qp[tid] = acc;
    }
    __syncthreads();
    if (tid < 64)
        qs[tid] = qp[tid] + qp[tid + 64] + qp[tid + 128] + qp[tid + 192] + bqq[h * 64 + tid];
    __syncthreads();
    // scores (thread = s)
    const float* kb = khT + (size_t)bh * 64 * 256;   // [dh][s]
    float sc = 0.f;
    #pragma unroll 8
    for (int dh = 0; dh < 64; ++dh) sc += qs[dh] * kb[dh * 256 + tid];
    sc *= 0.125f;
    red[tid] = sc; __syncthreads();
    for (int off = 128; off; off >>= 1) { if (tid < off) red[tid] = fmaxf(red[tid], red[tid + off]); __syncthreads(); }
    float mx = red[0]; __syncthreads();
    float e = expf(sc - mx);
    red[tid] = e; __syncthreads();
    for (int off = 128; off; off >>= 1) { if (tid < off) red[tid] += red[tid + off]; __syncthreads(); }
    float inv = 1.f / red[0];
    ps[tid] = e * inv;
    __syncthreads();
    int dh = tid & 63, ch = tid >> 6;
    const float* vb = vh + (size_t)bh * 256 * 64;    // [s][dh]
    float acc = 0.f;
    for (int s = ch * 64; s < ch * 64 + 64; ++s) acc += ps[s] * vb[s * 64 + dh];
    red[tid] = acc; __syncthreads();
    if (tid < 128) red[tid] += red[tid + 128];
    __syncthreads();
    if (tid < 64) obuf[b * 512 + h * 64 + tid] = red[tid] + red[tid + 64];
}

// ---------------------------------------------------------------------------
// K2: full-K synapse GEMM. u[b][c] = [obuf|act][b][:] @ [W2;syn_w][:, c].
// Grid 256 blocks = 16-col tiles. 256 threads = 4 colgroups x 32 rows x
// 2 k-halves (LDS-reduced). A staged in LDS in 160-k chunks.
// ---------------------------------------------------------------------------
#define SYN_PAD 164
__global__ __launch_bounds__(256) void k2_syn(
    const float* __restrict__ obuf, const float* __restrict__ act,
    const float* __restrict__ W2, const float* __restrict__ syn_w,
    float* __restrict__ u)
{
    __shared__ float As[2 * 32 * SYN_PAD];   // 42 KB
    int tid = threadIdx.x;
    int cgr = tid & 3, r = (tid >> 2) & 31, kh = tid >> 7;
    int c = blockIdx.x * 16 + cgr * 4;
    float acc0 = 0.f, acc1 = 0.f, acc2 = 0.f, acc3 = 0.f;
    for (int ri = 0; ri < 8; ++ri) {
        __syncthreads();
        // stage both halves' 160-k chunks: 2*32*40 float4 = 2560, 10/thread
        for (int q = 0; q < 10; ++q) {
            int i = tid + q * 256;            // 0..2559
            int hh = i / 1280;
            int rem = i - hh * 1280;
            int rr = rem / 40;
            int kg = rem - rr * 40;
            int k = hh * 1280 + ri * 160 + kg * 4;
            float4 v;
            if (k < 512) v = *(const float4*)(obuf + rr * 512 + k);
            else         v = *(const float4*)(act + rr * 2048 + (k - 512));
            *(float4*)(As + hh * 32 * SYN_PAD + rr * SYN_PAD + kg * 4) = v;
        }
        __syncthreads();
        const float* Ar = As + kh * 32 * SYN_PAD + r * SYN_PAD;
        int kbase = kh * 1280 + ri * 160;
        for (int kk = 0; kk < 160; kk += 8) {
            float4 wreg[8];
            #pragma unroll
            for (int u8 = 0; u8 < 8; ++u8) {
                int kg = kbase + kk + u8;
                const float* wr = (kg < 512 ? W2 : syn_w) + (size_t)kg * 4096 + c;
                wreg[u8] = *(const float4*)wr;
            }
            #pragma unroll
            for (int u8 = 0; u8 < 8; ++u8) {
                float a = Ar[kk + u8];
                acc0 += a * wreg[u8].x; acc1 += a * wreg[u8].y;
                acc2 += a * wreg[u8].z; acc3 += a * wreg[u8].w;
            }
        }
    }
    // cross-k-half reduce via LDS (reuse As)
    __syncthreads();
    float* red = As;
    if (kh == 1) {
        float* p = red + (r * 4 + cgr) * 4;
        p[0] = acc0; p[1] = acc1; p[2] = acc2; p[3] = acc3;
    }
    __syncthreads();
    if (kh == 0) {
        const float* p = red + (r * 4 + cgr) * 4;
        *(float4*)(u + r * 4096 + c) =
            make_float4(acc0 + p[0], acc1 + p[1], acc2 + p[2], acc3 + p[3]);
    }
}

// ---------------------------------------------------------------------------
// K3: bias + GLU + LayerNorm -> trace row. 32 blocks (b) x 256 threads.
// ---------------------------------------------------------------------------
__global__ __launch_bounds__(256) void k3_gluln(
    const float* __restrict__ u, const float* __restrict__ bias2,
    const float* __restrict__ g, const float* __restrict__ bta,
    float* __restrict__ trace, int t_iter)
{
    __shared__ float red[256];
    int b = blockIdx.x, tid = threadIdx.x;
    const float* ub = u + (size_t)b * 4096;
    float4 vals[2];
    float loc = 0.f;
    #pragma unroll
    for (int ii = 0; ii < 2; ++ii) {
        int d = (tid + ii * 256) * 4;
        float4 xa = *(const float4*)(ub + d);
        float4 xb = *(const float4*)(ub + 2048 + d);
        float4 ba = *(const float4*)(bias2 + d);
        float4 bb = *(const float4*)(bias2 + 2048 + d);
        float4 gl;
        gl.x = (xa.x + ba.x) * (1.f / (1.f + expf(-(xb.x + bb.x))));
        gl.y = (xa.y + ba.y) * (1.f / (1.f + expf(-(xb.y + bb.y))));
        gl.z = (xa.z + ba.z) * (1.f / (1.f + expf(-(xb.z + bb.z))));
        gl.w = (xa.w + ba.w) * (1.f / (1.f + expf(-(xb.w + bb.w))));
        vals[ii] = gl;
        loc += gl.x + gl.y + gl.z + gl.w;
    }
    red[tid] = loc; __syncthreads();
    for (int off = 128; off; off >>= 1) { if (tid < off) red[tid] += red[tid + off]; __syncthreads(); }
    float mu = red[0] * (1.f / 2048.f); __syncthreads();
    float l2 = 0.f;
    #pragma unroll
    for (int ii = 0; ii < 2; ++ii) {
        float4 v = vals[ii];
        float a = v.x - mu, b2 = v.y - mu, c2 = v.z - mu, d2 = v.w - mu;
        l2 += a * a + b2 * b2 + c2 * c2 + d2 * d2;
    }
    red[tid] = l2; __syncthreads();
    for (int off = 128; off; off >>= 1) { if (tid < off) red[tid] += red[tid + off]; __syncthreads(); }
    float rstd = 1.f / sqrtf(red[0] * (1.f / 2048.f) + 1e-5f);
    float* trow = trace + ((size_t)b * MM + (t_iter % MM)) * DD;
    #pragma unroll
    for (int ii = 0; ii < 2; ++ii) {
        int d = (tid + ii * 256) * 4;
        float4 gv = *(const float4*)(g + d);
        float4 bv = *(const float4*)(bta + d);
        float4 v = vals[ii];
        float4 o;
        o.x = (v.x - mu) * rstd * gv.x + bv.x;
        o.y = (v.y - mu) * rstd * gv.y + bv.y;
        o.z = (v.z - mu) * rstd * gv.z + bv.z;
        o.w = (v.w - mu) * rstd * gv.w + bv.w;
        *(float4*)(trow + d) = o;
    }
}

// ---------------------------------------------------------------------------
// K4: per-neuron MLP (unchanged from the proven launch version)
// ---------------------------------------------------------------------------
__global__ __launch_bounds__(256) void k4_nlm(
    const float* __restrict__ trace, const float* __restrict__ w1,
    const float* __restrict__ b1, const float* __restrict__ w2,
    const float* __restrict__ b2, float* __restrict__ act, int t_iter)
{
    int i = blockIdx.x * 256 + threadIdx.x;
    int b = i >> 11, d = i & 2047;
    float hp[32];
    #pragma unroll
    for (int h = 0; h < 32; h++) hp[h] = b1[d * 32 + h];
    const float* tr = trace + (size_t)b * MM * DD;
    for (int m = 0; m < 25; m++) {
        int mph = (t_iter + 1 + m) % 25;      // logical->physical circular map
        float tv = tr[mph * DD + d];
        #pragma unroll
        for (int h = 0; h < 32; h++) hp[h] += tv * w1[((size_t)m * 32 + h) * DD + d];
    }
    float o0 = b2[d * 2], o1 = b2[d * 2 + 1];
    #pragma unroll
    for (int h = 0; h < 16; h++) {
        float hv = hp[h] * (1.f / (1.f + expf(-hp[h + 16])));
        o0 += hv * w2[((size_t)h * 2) * DD + d];
        o1 += hv * w2[((size_t)h * 2 + 1) * DD + d];
    }
    act[i] = o0 * (1.f / (1.f + expf(-o1)));
}

// ---------------------------------------------------------------------------
// K5: sync_o fused into pred GEMM. 32 blocks = 32-col tiles; each block
// computes the full sync_o (32x512) into XOR-swizzled LDS (conflict-free),
// block 0 writes the ping-pong state. Then full-K (512) col-tile GEMM.
// ---------------------------------------------------------------------------
__global__ __launch_bounds__(256) void k5_predsync(
    const float* __restrict__ act, const int* __restrict__ lo, const int* __restrict__ ro,
    const float* __restrict__ r_o,
    const float* __restrict__ aold, const float* __restrict__ bold,
    float* __restrict__ anew, float* __restrict__ bnew,
    const float* __restrict__ out_w, float* __restrict__ predt,
    float* __restrict__ out_sync, int t_iter)
{
    __shared__ float sa[32 * 512];   // 64 KB, XOR-swizzled: j ^ ((r&7)<<3)
    int tid = threadIdx.x, blk = blockIdx.x;
    for (int q = 0; q < 64; ++q) {
        int idx = tid + q * 256;          // 0..16383
        int r = idx >> 9, j = idx & 511;
        float p = act[r * 2048 + lo[j]] * act[r * 2048 + ro[j]];
        float rr = r_o[j];
        float aa = rr * aold[r * 512 + j] + p;
        float bb = rr * bold[r * 512 + j] + 1.f;
        float s = aa / sqrtf(bb);
        sa[r * 512 + (j ^ ((r & 7) << 3))] = s;
        if (blk == 0) {
            anew[r * 512 + j] = aa;
            bnew[r * 512 + j] = bb;
            if (t_iter == TT - 1) out_sync[r * 512 + j] = s;
        }
    }
    __syncthreads();
    int cgr = tid & 7, r = tid >> 3;
    int c = blk * 32 + cgr * 4;
    if (c < 1000) {
        float acc0 = 0.f, acc1 = 0.f, acc2 = 0.f, acc3 = 0.f;
        int sw = (r & 7) << 3;
        const float* sar = sa + r * 512;
        for (int k = 0; k < 512; k += 8) {
            float4 wreg[8];
            #pragma unroll
            for (int u8 = 0; u8 < 8; ++u8)
                wreg[u8] = *(const float4*)(out_w + (size_t)(k + u8) * 1000 + c);
            #pragma unroll
            for (int u8 = 0; u8 < 8; ++u8) {
                float a = sar[(k + u8) ^ sw];
                acc0 += a * wreg[u8].x; acc1 += a * wreg[u8].y;
                acc2 += a * wreg[u8].z; acc3 += a * wreg[u8].w;
            }
        }
        *(float4*)(predt + (size_t)t_iter * 32000 + r * 1000 + c) =
            make_float4(acc0, acc1, acc2, acc3);
    }
}

// ---------------------------------------------------------------------------
// K6: deferred certainty + prediction write-out for ALL ticks.
// Grid 1600 blocks = (t, b).
// ---------------------------------------------------------------------------
__global__ __launch_bounds__(256) void k6_cert(
    const float* __restrict__ predt, const float* __restrict__ out_b,
    float* __restrict__ d_out)
{
    int t_iter = blockIdx.x >> 5, b = blockIdx.x & 31, t = threadIdx.x;
    __shared__ float red[256];
    const float* pr = predt + (size_t)t_iter * 32000 + b * 1000;
    float pv[4];
    float mx = -1e30f;
    #pragma unroll
    for (int ii = 0; ii < 4; ++ii) {
        int c = t + ii * 256;
        float v = -1e30f;
        if (c < 1000) {
            v = out_b[c] + pr[c];
            d_out[(size_t)b * NOUT * TT + (size_t)c * TT + t_iter] = v;
        }
        pv[ii] = v;
        mx = fmaxf(mx, v);
    }
    red[t] = mx; __syncthreads();
    for (int off = 128; off; off >>= 1) { if (t < off) red[t] = fmaxf(red[t], red[t + off]); __syncthreads(); }
    mx = red[0]; __syncthreads();
    float s1 = 0.f, s2 = 0.f;
    #pragma unroll
    for (int ii = 0; ii < 4; ++ii) {
        int c = t + ii * 256;
        if (c < 1000) { float xx = pv[ii] - mx; float e = expf(xx); s1 += e; s2 += e * xx; }
    }
    red[t] = s1; __syncthreads();
    for (int off = 128; off; off >>= 1) { if (t < off) red[t] += red[t + off]; __syncthreads(); }
    s1 = red[0]; __syncthreads();
    red[t] = s2; __syncthreads();
    for (int off = 128; off; off >>= 1) { if (t < off) red[t] += red[t + off]; __syncthreads(); }
    s2 = red[0];
    if (t == 0) {
        float ne = -(s2 / s1 - logf(s1)) * (1.f / logf(1000.f));
        size_t base = (size_t)BB * NOUT * TT + (size_t)b * 2 * TT + t_iter;
        d_out[base] = ne;
        d_out[base + TT] = 1.f - ne;
    }
}

// ---------------------------------------------------------------------------
extern "C" void kernel_launch(void* const* d_in, const int* in_sizes, int n_in,
                              void* d_out, int out_size, void* d_ws, size_t ws_size,
                              hipStream_t stream)
{
    const float* x        = (const float*)d_in[0];
    const float* kv_w     = (const float*)d_in[1];
    const float* kv_b     = (const float*)d_in[2];
    const float* ln_kv_g  = (const float*)d_in[3];
    const float* ln_kv_b  = (const float*)d_in[4];
    const float* q_w      = (const float*)d_in[5];
    const float* q_b      = (const float*)d_in[6];
    const float* Wq       = (const float*)d_in[7];
    const float* bq       = (const float*)d_in[8];
    const float* Wk       = (const float*)d_in[9];
    const float* bk       = (const float*)d_in[10];
    const float* Wv       = (const float*)d_in[11];
    const float* bv       = (const float*)d_in[12];
    const float* Wo       = (const float*)d_in[13];
    const float* bo       = (const float*)d_in[14];
    const float* syn_w    = (const float*)d_in[15];
    const float* syn_b    = (const float*)d_in[16];
    const float* ln_syn_g = (const float*)d_in[17];
    const float* ln_syn_b = (const float*)d_in[18];
    const float* nlm_w1   = (const float*)d_in[19];
    const float* nlm_b1   = (const float*)d_in[20];
    const float* nlm_w2   = (const float*)d_in[21];
    const float* nlm_b2   = (const float*)d_in[22];
    const float* out_w    = (const float*)d_in[23];
    const float* out_b    = (const float*)d_in[24];
    const float* dec_a    = (const float*)d_in[25];
    const float* dec_o    = (const float*)d_in[26];
    const float* start_tr = (const float*)d_in[27];
    const float* start_ac = (const float*)d_in[28];
    const int*   idx_la   = (const int*)d_in[29];
    const int*   idx_ra   = (const int*)d_in[30];
    const int*   idx_lo   = (const int*)d_in[31];
    const int*   idx_ro   = (const int*)d_in[32];
    float* out = (float*)d_out;

    // workspace carve (floats)
    float* w = (float*)d_ws;
    float* kvbuf = w;            w += (size_t)8192 * 512;
    float* khT   = w;            w += (size_t)8192 * 512;
    float* vhb   = w;            w += (size_t)8192 * 512;
    float* Wqq   = w;            w += (size_t)512 * 512;
    float* bqq   = w;            w += 512;
    float* W2    = w;            w += (size_t)512 * 4096;
    float* bias2 = w;            w += 4096;
    float* r_a   = w;            w += 512;
    float* r_o   = w;            w += 512;
    float* a_a   = w;            w += 2 * BB * NSA;           // ping-pong
    float* b_a   = w;            w += 2 * BB * NSA;
    float* a_o   = w;            w += 2 * BB * NSO;
    float* b_o   = w;            w += 2 * BB * NSO;
    float* act   = w;            w += BB * DD;
    float* trace = w;            w += (size_t)BB * MM * DD;
    float* obuf  = w;            w += BB * DIN;
    float* ubuf  = w;            w += (size_t)BB * 4096;      // synapse pre-GLU
    float* predt = w;            w += (size_t)TT * BB * 1000; // all-tick preds

    // ---- precompute ----
    init_kernel<<<6400, 256, 0, stream>>>(dec_a, dec_o, start_ac, start_tr, idx_lo, idx_ro,
                                          r_a, r_o, a_a, b_a, a_o, b_o, act, trace);
    gemm64<1, 0><<<dim3(128, 8), 256, 0, stream>>>(x, kv_w, kv_b, kvbuf, 8192, 512, 512);
    ln_rows<<<8192, 256, 0, stream>>>(kvbuf, ln_kv_g, ln_kv_b);
    gemm64<0, 1><<<dim3(128, 8), 256, 0, stream>>>(kvbuf, Wk, bk, khT, 8192, 512, 512);
    gemm64<0, 2><<<dim3(128, 8), 256, 0, stream>>>(kvbuf, Wv, bv, vhb, 8192, 512, 512);
    gemm64<0, 0><<<dim3(8, 8), 256, 0, stream>>>(q_w, Wq, nullptr, Wqq, 512, 512, 512);
    bqq_kernel<<<2, 256, 0, stream>>>(q_b, Wq, bq, bqq);
    gemm64<0, 0><<<dim3(8, 64), 256, 0, stream>>>(Wo, syn_w, nullptr, W2, 512, 4096, 512);
    bias2_kernel<<<16, 256, 0, stream>>>(bo, syn_w, syn_b, bias2);

    float* out_sync = out + (size_t)BB * NOUT * TT + (size_t)BB * 2 * TT;

    // ---- recurrent ticks: 5 dispatches each ----
    for (int t = 0; t < TT; ++t) {
        int par = t & 1;
        k1_front<<<256, 256, 0, stream>>>(act, idx_la, idx_ra, r_a,
                                          a_a + par * (BB * 512), b_a + par * (BB * 512),
                                          a_a + (par ^ 1) * (BB * 512), b_a + (par ^ 1) * (BB * 512),
                                          Wqq, bqq, khT, vhb, obuf);
        k2_syn<<<256, 256, 0, stream>>>(obuf, act, W2, syn_w, ubuf);
        k3_gluln<<<32, 256, 0, stream>>>(ubuf, bias2, ln_syn_g, ln_syn_b, trace, t);
        k4_nlm<<<256, 256, 0, stream>>>(trace, nlm_w1, nlm_b1, nlm_w2, nlm_b2, act, t);
        k5_predsync<<<32, 256, 0, stream>>>(act, idx_lo, idx_ro, r_o,
                                            a_o + par * (BB * 512), b_o + par * (BB * 512),
                                            a_o + (par ^ 1) * (BB * 512), b_o + (par ^ 1) * (BB * 512),
                                            out_w, predt, out_sync, t);
    }
    // deferred: certainty + prediction layout for all 50 ticks in one launch
    k6_cert<<<1600, 256, 0, stream>>>(predt, out_b, out);
}

// Round 6
// 5208.826 us; speedup vs baseline: 5.3972x; 1.7793x over previous
//
#include <hip/hip_runtime.h>
#include <math.h>

// Problem constants
#define BB 32
#define CC 512
#define SS 256      // kv tokens
#define DD 2048     // d_model
#define DIN 512
#define NH 8
#define DHD 64
#define TT 50
#define MM 25
#define HHID 16
#define NSA 512
#define NSO 512
#define NOUT 1000

// ---------------------------------------------------------------------------
// Init: decays, sync states, trace0  (act0 slot written later by pad_act0,
// because acthist aliases kvbuf which the precompute GEMMs still need)
// ---------------------------------------------------------------------------
__global__ void init_kernel(const float* __restrict__ dec_a, const float* __restrict__ dec_o,
                            const float* __restrict__ start_act, const float* __restrict__ start_trace,
                            const int* __restrict__ idx_lo, const int* __restrict__ idx_ro,
                            float* __restrict__ r_a, float* __restrict__ r_o,
                            float* __restrict__ a_a, float* __restrict__ b_a,
                            float* __restrict__ a_o, float* __restrict__ b_o,
                            float* __restrict__ trace)
{
    int i = blockIdx.x * 256 + threadIdx.x;
    if (i < 512) {
        r_a[i] = expf(-fminf(fmaxf(dec_a[i], 0.f), 15.f));
        r_o[i] = expf(-fminf(fmaxf(dec_o[i], 0.f), 15.f));
    }
    if (i < BB * NSA) {
        a_a[i] = 0.f; b_a[i] = 0.f;
        int j = i & 511;
        a_o[i] = start_act[idx_lo[j]] * start_act[idx_ro[j]];
        b_o[i] = 1.f;
    }
    if (i < BB * MM * DD) {
        int rem = i % (MM * DD);
        int m = rem / DD, d = rem % DD;
        trace[i] = start_trace[d * MM + m];   // start_trace is (D,M)
    }
}

// ---------------------------------------------------------------------------
// Generic 64x64 tiled GEMM. AMODE 0: row-major A. AMODE 1: A is x (B,C,S).
// SMODE 0: row-major + bias. SMODE 1: khT (B,H,DH,S). SMODE 2: vh (B,H,S,DH).
// Requires Mdim%64==0, Ndim%64==0.
// ---------------------------------------------------------------------------
template<int AMODE, int SMODE>
__global__ void gemm64(const float* __restrict__ A, const float* __restrict__ Bm,
                       const float* __restrict__ bias, float* __restrict__ Cm,
                       int Mdim, int Ndim, int Kdim)
{
    __shared__ float As[16 * 65];
    __shared__ float Bs[16 * 64];
    int row0 = blockIdx.x * 64;
    int col0 = blockIdx.y * 64;
    int t = threadIdx.x;
    int tx = t & 15, ty = t >> 4;
    float acc[4][4] = {};
    for (int k0 = 0; k0 < Kdim; k0 += 16) {
        if (AMODE == 0) {
            for (int i = t; i < 1024; i += 256) {
                int kk = i & 15, r = i >> 4;
                As[kk * 65 + r] = A[(size_t)(row0 + r) * Kdim + k0 + kk];
            }
        } else {
            int b = row0 / SS, s0 = row0 % SS;
            for (int i = t; i < 1024; i += 256) {
                int r = i & 63, kk = i >> 6;
                As[kk * 65 + r] = A[((size_t)b * CC + k0 + kk) * SS + s0 + r];
            }
        }
        for (int i = t; i < 1024; i += 256) {
            int c = i & 63, kk = i >> 6;
            Bs[kk * 64 + c] = Bm[(size_t)(k0 + kk) * Ndim + col0 + c];
        }
        __syncthreads();
        #pragma unroll
        for (int kk = 0; kk < 16; ++kk) {
            float a[4], bb[4];
            #pragma unroll
            for (int i = 0; i < 4; i++) a[i] = As[kk * 65 + ty * 4 + i];
            #pragma unroll
            for (int j = 0; j < 4; j++) bb[j] = Bs[kk * 64 + tx * 4 + j];
            #pragma unroll
            for (int i = 0; i < 4; i++)
                #pragma unroll
                for (int j = 0; j < 4; j++) acc[i][j] += a[i] * bb[j];
        }
        __syncthreads();
    }
    #pragma unroll
    for (int i = 0; i < 4; i++)
        #pragma unroll
        for (int j = 0; j < 4; j++) {
            int row = row0 + ty * 4 + i, col = col0 + tx * 4 + j;
            float v = acc[i][j] + (bias ? bias[col] : 0.f);
            if (SMODE == 0) {
                Cm[(size_t)row * Ndim + col] = v;
            } else if (SMODE == 1) {
                int b = row / SS, s = row % SS, h = col >> 6, dh = col & 63;
                Cm[(((size_t)b * NH + h) * DHD + dh) * SS + s] = v;
            } else {
                int b = row / SS, s = row % SS, h = col >> 6, dh = col & 63;
                Cm[(((size_t)b * NH + h) * SS + s) * DHD + dh] = v;
            }
        }
}

// LayerNorm over rows of 512 (in place)
__global__ void ln_rows(float* __restrict__ buf, const float* __restrict__ g,
                        const float* __restrict__ bta)
{
    int row = blockIdx.x, t = threadIdx.x;
    __shared__ float red[256];
    float v0 = buf[(size_t)row * 512 + t];
    float v1 = buf[(size_t)row * 512 + 256 + t];
    red[t] = v0 + v1; __syncthreads();
    for (int off = 128; off; off >>= 1) { if (t < off) red[t] += red[t + off]; __syncthreads(); }
    float mu = red[0] * (1.f / 512.f); __syncthreads();
    float d0 = v0 - mu, d1 = v1 - mu;
    red[t] = d0 * d0 + d1 * d1; __syncthreads();
    for (int off = 128; off; off >>= 1) { if (t < off) red[t] += red[t + off]; __syncthreads(); }
    float rstd = 1.f / sqrtf(red[0] * (1.f / 512.f) + 1e-5f);
    buf[(size_t)row * 512 + t]       = d0 * rstd * g[t] + bta[t];
    buf[(size_t)row * 512 + 256 + t] = d1 * rstd * g[t + 256] + bta[t + 256];
}

__global__ void bqq_kernel(const float* __restrict__ q_b, const float* __restrict__ Wq,
                           const float* __restrict__ bq, float* __restrict__ bqq)
{
    int c = blockIdx.x * 256 + threadIdx.x;
    if (c >= 512) return;
    float acc = bq[c];
    for (int k = 0; k < 512; k++) acc += q_b[k] * Wq[k * 512 + c];
    bqq[c] = acc;
}

__global__ void bias2_kernel(const float* __restrict__ bo, const float* __restrict__ syn_w,
                             const float* __restrict__ syn_b, float* __restrict__ bias2)
{
    int c = blockIdx.x * 256 + threadIdx.x;
    if (c >= 4096) return;
    float acc = syn_b[c];
    for (int k = 0; k < 512; k++) acc += bo[k] * syn_w[(size_t)k * 4096 + c];
    bias2[c] = acc;
}

// Pad out_w to 1024 cols (zeros), pad out_b, and write act0 into acthist
// slot 0 (must run AFTER the kvbuf-consuming GEMMs since acthist aliases it).
__global__ void pad_act0(const float* __restrict__ out_w, const float* __restrict__ out_b,
                         const float* __restrict__ start_act,
                         float* __restrict__ out_wp, float* __restrict__ out_bp,
                         float* __restrict__ act0slot)
{
    int i = blockIdx.x * 256 + threadIdx.x;
    if (i < 512 * 1024) {
        int r = i >> 10, c = i & 1023;
        out_wp[i] = (c < 1000) ? out_w[r * 1000 + c] : 0.f;
    }
    if (i < 1024) out_bp[i] = (i < 1000) ? out_b[i] : 0.f;
    if (i < BB * DD) act0slot[i] = start_act[i & (DD - 1)];
}

// ---------------------------------------------------------------------------
// K1: sync_a + q-projection slice + attention. Block = (b,h), 256 threads.
// ---------------------------------------------------------------------------
__global__ __launch_bounds__(256) void k1_front(
    const float* __restrict__ act, const int* __restrict__ la, const int* __restrict__ ra,
    const float* __restrict__ r_a,
    const float* __restrict__ aold, const float* __restrict__ bold,
    float* __restrict__ anew, float* __restrict__ bnew,
    const float* __restrict__ Wqq, const float* __restrict__ bqq,
    const float* __restrict__ khT, const float* __restrict__ vh,
    float* __restrict__ obuf)
{
    __shared__ float sa[512];
    __shared__ float qp[256];
    __shared__ float qs[64];
    __shared__ float ps[256];
    __shared__ float red[256];
    int bh = blockIdx.x, b = bh >> 3, h = bh & 7;
    int tid = threadIdx.x;
    const float* actb = act + b * DD;
    for (int j = tid; j < 512; j += 256) {
        float p = actb[la[j]] * actb[ra[j]];
        float r = r_a[j];
        float aa = r * aold[b * 512 + j] + p;
        float bb = r * bold[b * 512 + j] + 1.f;
        sa[j] = aa / sqrtf(bb);
        if (h == 0) { anew[b * 512 + j] = aa; bnew[b * 512 + j] = bb; }
    }
    __syncthreads();
    {
        int cl = tid & 63, q = tid >> 6;
        const float* wcol = Wqq + h * 64 + cl;
        float acc = 0.f;
        #pragma unroll 8
        for (int k = q * 128; k < q * 128 + 128; ++k)
            acc += sa[k] * wcol[k * 512];
        qp[tid] = acc;
    }
    __syncthreads();
    if (tid < 64)
        qs[tid] = qp[tid] + qp[tid + 64] + qp[tid + 128] + qp[tid + 192] + bqq[h * 64 + tid];
    __syncthreads();
    const float* kb = khT + (size_t)bh * 64 * 256;   // [dh][s]
    float sc = 0.f;
    #pragma unroll 8
    for (int dh = 0; dh < 64; ++dh) sc += qs[dh] * kb[dh * 256 + tid];
    sc *= 0.125f;
    red[tid] = sc; __syncthreads();
    for (int off = 128; off; off >>= 1) { if (tid < off) red[tid] = fmaxf(red[tid], red[tid + off]); __syncthreads(); }
    float mx = red[0]; __syncthreads();
    float e = expf(sc - mx);
    red[tid] = e; __syncthreads();
    for (int off = 128; off; off >>= 1) { if (tid < off) red[tid] += red[tid + off]; __syncthreads(); }
    float inv = 1.f / red[0];
    ps[tid] = e * inv;
    __syncthreads();
    int dh = tid & 63, ch = tid >> 6;
    const float* vb = vh + (size_t)bh * 256 * 64;    // [s][dh]
    float acc = 0.f;
    for (int s = ch * 64; s < ch * 64 + 64; ++s) acc += ps[s] * vb[s * 64 + dh];
    red[tid] = acc; __syncthreads();
    if (tid < 128) red[tid] += red[tid + 128];
    __syncthreads();
    if (tid < 64) obuf[b * 512 + h * 64 + tid] = red[tid] + red[tid + 64];
}

// ---------------------------------------------------------------------------
// K2: synapse GEMM, 4-way k-split. Grid 512 = (ct 0..127 x 32 cols, ks 0..3
// x 640 k). Per thread: 1 row x 4 cols, K=640. Weight wave-loads = 128B
// coalesced (8 cgr x float4). A staged in LDS in 160-k chunks.
// ---------------------------------------------------------------------------
#define SYN_PAD 164
__global__ __launch_bounds__(256) void k2_syn(
    const float* __restrict__ obuf, const float* __restrict__ act,
    const float* __restrict__ W2, const float* __restrict__ syn_w,
    float* __restrict__ upart)
{
    __shared__ float As[32 * SYN_PAD];   // 21 KB
    int tid = threadIdx.x;
    int ks = blockIdx.x & 3, ct = blockIdx.x >> 2;
    int cgr = tid & 7, r = tid >> 3;     // 8 colgroups x 32 rows
    int c = ct * 32 + cgr * 4;
    int kbase0 = ks * 640;
    float acc0 = 0.f, acc1 = 0.f, acc2 = 0.f, acc3 = 0.f;
    for (int ri = 0; ri < 4; ++ri) {
        __syncthreads();
        // stage 32 rows x 160 k = 1280 float4, 5 per thread
        #pragma unroll
        for (int q = 0; q < 5; ++q) {
            int i = tid + q * 256;            // 0..1279
            int rr = i / 40, kg = i % 40;
            int k = kbase0 + ri * 160 + kg * 4;
            float4 v;
            if (k < 512) v = *(const float4*)(obuf + rr * 512 + k);
            else         v = *(const float4*)(act + rr * 2048 + (k - 512));
            *(float4*)(As + rr * SYN_PAD + kg * 4) = v;
        }
        __syncthreads();
        const float* Ar = As + r * SYN_PAD;
        int kbase = kbase0 + ri * 160;
        for (int kk = 0; kk < 160; kk += 8) {
            float4 wreg[8];
            #pragma unroll
            for (int u8 = 0; u8 < 8; ++u8) {
                int kg = kbase + kk + u8;
                const float* wr = (kg < 512 ? W2 : syn_w) + (size_t)kg * 4096 + c;
                wreg[u8] = *(const float4*)wr;
            }
            #pragma unroll
            for (int u8 = 0; u8 < 8; ++u8) {
                float a = Ar[kk + u8];
                acc0 += a * wreg[u8].x; acc1 += a * wreg[u8].y;
                acc2 += a * wreg[u8].z; acc3 += a * wreg[u8].w;
            }
        }
    }
    *(float4*)(upart + (size_t)ks * (32 * 4096) + r * 4096 + c) =
        make_float4(acc0, acc1, acc2, acc3);
}

// ---------------------------------------------------------------------------
// K34: glu_ln + nlm fused. Grid 256 = (b 0..31, dtile 0..7), 256 threads.
// Each block redundantly computes the full row-LN (L2-hot reads), then the
// per-neuron MLP for its 256-d slice; newest trace value stays in-register.
// Writes trace row slice AND act (into acthist slot t+1).
// ---------------------------------------------------------------------------
__global__ __launch_bounds__(256) void k34_glunlm(
    const float* __restrict__ upart, const float* __restrict__ bias2,
    const float* __restrict__ g, const float* __restrict__ bta,
    float* __restrict__ trace,
    const float* __restrict__ w1, const float* __restrict__ b1,
    const float* __restrict__ w2, const float* __restrict__ b2,
    float* __restrict__ actout, int t_iter)
{
    __shared__ float red[256];
    int blk = blockIdx.x, tid = threadIdx.x;
    int b = blk >> 3, dtile = blk & 7;
    const float* u0 = upart + (size_t)b * 4096;
    // GLU over the full row (8 d per thread), accumulate sum
    float vals[8];
    float loc = 0.f;
    #pragma unroll
    for (int ii = 0; ii < 8; ++ii) {
        int d = tid + ii * 256;
        float a = bias2[d], bb = bias2[d + 2048];
        #pragma unroll
        for (int ks = 0; ks < 4; ++ks) {
            const float* up = u0 + (size_t)ks * (32 * 4096);
            a += up[d];
            bb += up[d + 2048];
        }
        float gl = a * (1.f / (1.f + expf(-bb)));
        vals[ii] = gl; loc += gl;
    }
    red[tid] = loc; __syncthreads();
    for (int off = 128; off; off >>= 1) { if (tid < off) red[tid] += red[tid + off]; __syncthreads(); }
    float mu = red[0] * (1.f / 2048.f); __syncthreads();
    float l2 = 0.f;
    #pragma unroll
    for (int ii = 0; ii < 8; ++ii) { float dq = vals[ii] - mu; l2 += dq * dq; }
    red[tid] = l2; __syncthreads();
    for (int off = 128; off; off >>= 1) { if (tid < off) red[tid] += red[tid + off]; __syncthreads(); }
    float rstd = 1.f / sqrtf(red[0] * (1.f / 2048.f) + 1e-5f);
    // this thread's d in the block's slice (recompute gl to avoid dynamic
    // indexing of vals[] -> scratch; loads are L2-hot)
    int d0 = dtile * 256 + tid;
    float a0 = bias2[d0], bb0 = bias2[d0 + 2048];
    #pragma unroll
    for (int ks = 0; ks < 4; ++ks) {
        const float* up = u0 + (size_t)ks * (32 * 4096);
        a0 += up[d0];
        bb0 += up[d0 + 2048];
    }
    float gl0 = a0 * (1.f / (1.f + expf(-bb0)));
    float nv = (gl0 - mu) * rstd * g[d0] + bta[d0];
    int newrow = t_iter % MM;
    trace[((size_t)b * MM + newrow) * DD + d0] = nv;
    // NLM for d0: 24 old rows from global + newest in-register
    float hp[32];
    #pragma unroll
    for (int h = 0; h < 32; h++) hp[h] = b1[d0 * 32 + h];
    const float* tr = trace + (size_t)b * MM * DD;
    for (int m = 0; m < 24; m++) {
        int mph = (t_iter + 1 + m) % 25;
        float tv = tr[mph * DD + d0];
        #pragma unroll
        for (int h = 0; h < 32; h++) hp[h] += tv * w1[((size_t)m * 32 + h) * DD + d0];
    }
    #pragma unroll
    for (int h = 0; h < 32; h++) hp[h] += nv * w1[((size_t)24 * 32 + h) * DD + d0];
    float o0 = b2[d0 * 2], o1 = b2[d0 * 2 + 1];
    #pragma unroll
    for (int h = 0; h < 16; h++) {
        float hv = hp[h] * (1.f / (1.f + expf(-hp[h + 16])));
        o0 += hv * w2[((size_t)h * 2) * DD + d0];
        o1 += hv * w2[((size_t)h * 2 + 1) * DD + d0];
    }
    actout[b * DD + d0] = o0 * (1.f / (1.f + expf(-o1)));
}

// ---------------------------------------------------------------------------
// Post: sync_o linear recurrence over all 50 ticks. 64 blocks x 256 threads,
// thread = (b,j). Writes so_hist[t][b][j] and out_sync.
// ---------------------------------------------------------------------------
__global__ __launch_bounds__(256) void k_syncscan(
    const float* __restrict__ acthist, const int* __restrict__ lo, const int* __restrict__ ro,
    const float* __restrict__ r_o,
    const float* __restrict__ a_o0, const float* __restrict__ b_o0,
    float* __restrict__ so_hist, float* __restrict__ out_sync)
{
    int idx = blockIdx.x * 256 + threadIdx.x;   // 0..16383
    int b = idx >> 9, j = idx & 511;
    float aa = a_o0[idx], bb = b_o0[idx];
    float rr = r_o[j];
    int il = lo[j], ir = ro[j];
    const float* ah = acthist + (size_t)(BB * DD) + b * DD;   // slot 1 = act after tick 0
    float s = 0.f;
    for (int t = 0; t < TT; ++t) {
        float p = ah[il] * ah[ir];
        aa = rr * aa + p;
        bb = rr * bb + 1.f;
        s = aa / sqrtf(bb);
        so_hist[(size_t)t * (BB * 512) + idx] = s;
        ah += BB * DD;
    }
    out_sync[idx] = s;
}

// ---------------------------------------------------------------------------
// Post: certainty + prediction write-out for ALL ticks. Grid 1600 = (t, b).
// predt rows are (t*32+b), stride 1024, bias already included.
// ---------------------------------------------------------------------------
__global__ __launch_bounds__(256) void k6_cert(
    const float* __restrict__ predt, float* __restrict__ d_out)
{
    int t_iter = blockIdx.x >> 5, b = blockIdx.x & 31, t = threadIdx.x;
    __shared__ float red[256];
    const float* pr = predt + ((size_t)t_iter * 32 + b) * 1024;
    float pv[4];
    float mx = -1e30f;
    #pragma unroll
    for (int ii = 0; ii < 4; ++ii) {
        int c = t + ii * 256;
        float v = -1e30f;
        if (c < 1000) {
            v = pr[c];
            d_out[(size_t)b * NOUT * TT + (size_t)c * TT + t_iter] = v;
        }
        pv[ii] = v;
        mx = fmaxf(mx, v);
    }
    red[t] = mx; __syncthreads();
    for (int off = 128; off; off >>= 1) { if (t < off) red[t] = fmaxf(red[t], red[t + off]); __syncthreads(); }
    mx = red[0]; __syncthreads();
    float s1 = 0.f, s2 = 0.f;
    #pragma unroll
    for (int ii = 0; ii < 4; ++ii) {
        int c = t + ii * 256;
        if (c < 1000) { float xx = pv[ii] - mx; float e = expf(xx); s1 += e; s2 += e * xx; }
    }
    red[t] = s1; __syncthreads();
    for (int off = 128; off; off >>= 1) { if (t < off) red[t] += red[t + off]; __syncthreads(); }
    s1 = red[0]; __syncthreads();
    red[t] = s2; __syncthreads();
    for (int off = 128; off; off >>= 1) { if (t < off) red[t] += red[t + off]; __syncthreads(); }
    s2 = red[0];
    if (t == 0) {
        float ne = -(s2 / s1 - logf(s1)) * (1.f / logf(1000.f));
        size_t base = (size_t)BB * NOUT * TT + (size_t)b * 2 * TT + t_iter;
        d_out[base] = ne;
        d_out[base + TT] = 1.f - ne;
    }
}

// ---------------------------------------------------------------------------
extern "C" void kernel_launch(void* const* d_in, const int* in_sizes, int n_in,
                              void* d_out, int out_size, void* d_ws, size_t ws_size,
                              hipStream_t stream)
{
    const float* x        = (const float*)d_in[0];
    const float* kv_w     = (const float*)d_in[1];
    const float* kv_b     = (const float*)d_in[2];
    const float* ln_kv_g  = (const float*)d_in[3];
    const float* ln_kv_b  = (const float*)d_in[4];
    const float* q_w      = (const float*)d_in[5];
    const float* q_b      = (const float*)d_in[6];
    const float* Wq       = (const float*)d_in[7];
    const float* bq       = (const float*)d_in[8];
    const float* Wk       = (const float*)d_in[9];
    const float* bk       = (const float*)d_in[10];
    const float* Wv       = (const float*)d_in[11];
    const float* bv       = (const float*)d_in[12];
    const float* Wo       = (const float*)d_in[13];
    const float* bo       = (const float*)d_in[14];
    const float* syn_w    = (const float*)d_in[15];
    const float* syn_b    = (const float*)d_in[16];
    const float* ln_syn_g = (const float*)d_in[17];
    const float* ln_syn_b = (const float*)d_in[18];
    const float* nlm_w1   = (const float*)d_in[19];
    const float* nlm_b1   = (const float*)d_in[20];
    const float* nlm_w2   = (const float*)d_in[21];
    const float* nlm_b2   = (const float*)d_in[22];
    const float* out_w    = (const float*)d_in[23];
    const float* out_b    = (const float*)d_in[24];
    const float* dec_a    = (const float*)d_in[25];
    const float* dec_o    = (const float*)d_in[26];
    const float* start_tr = (const float*)d_in[27];
    const float* start_ac = (const float*)d_in[28];
    const int*   idx_la   = (const int*)d_in[29];
    const int*   idx_ra   = (const int*)d_in[30];
    const int*   idx_lo   = (const int*)d_in[31];
    const int*   idx_ro   = (const int*)d_in[32];
    float* out = (float*)d_out;

    // workspace carve (floats)
    float* w = (float*)d_ws;
    float* kvbuf = w;            w += (size_t)8192 * 512;     // 16.8MB; acthist aliases
    float* khT   = w;            w += (size_t)8192 * 512;
    float* vhb   = w;            w += (size_t)8192 * 512;
    float* Wqq   = w;            w += (size_t)512 * 512;
    float* bqq   = w;            w += 512;
    float* W2    = w;            w += (size_t)512 * 4096;
    float* bias2 = w;            w += 4096;
    float* r_a   = w;            w += 512;
    float* r_o   = w;            w += 512;
    float* a_a   = w;            w += 2 * BB * NSA;           // ping-pong
    float* b_a   = w;            w += 2 * BB * NSA;
    float* a_o   = w;            w += BB * NSO;
    float* b_o   = w;            w += BB * NSO;
    float* trace = w;            w += (size_t)BB * MM * DD;
    float* obuf  = w;            w += BB * DIN;
    float* upart = w;            w += (size_t)4 * 32 * 4096;  // 4 k-split partials
    float* so_hist = w;          w += (size_t)TT * BB * 512;  // 3.3MB
    float* predt = w;            w += (size_t)TT * BB * 1024; // 6.6MB
    float* out_wp = w;           w += (size_t)512 * 1024;
    float* out_bp = w;           w += 1024;

    // acthist: 51 slots of (BB*DD); slot 0 = initial act. Aliases kvbuf
    // (13.4MB <= 16.8MB), written only after the precompute GEMMs finish.
    float* acthist = kvbuf;

    // ---- precompute ----
    init_kernel<<<6400, 256, 0, stream>>>(dec_a, dec_o, start_ac, start_tr, idx_lo, idx_ro,
                                          r_a, r_o, a_a, b_a, a_o, b_o, trace);
    gemm64<1, 0><<<dim3(128, 8), 256, 0, stream>>>(x, kv_w, kv_b, kvbuf, 8192, 512, 512);
    ln_rows<<<8192, 256, 0, stream>>>(kvbuf, ln_kv_g, ln_kv_b);
    gemm64<0, 1><<<dim3(128, 8), 256, 0, stream>>>(kvbuf, Wk, bk, khT, 8192, 512, 512);
    gemm64<0, 2><<<dim3(128, 8), 256, 0, stream>>>(kvbuf, Wv, bv, vhb, 8192, 512, 512);
    gemm64<0, 0><<<dim3(8, 8), 256, 0, stream>>>(q_w, Wq, nullptr, Wqq, 512, 512, 512);
    bqq_kernel<<<2, 256, 0, stream>>>(q_b, Wq, bq, bqq);
    gemm64<0, 0><<<dim3(8, 64), 256, 0, stream>>>(Wo, syn_w, nullptr, W2, 512, 4096, 512);
    bias2_kernel<<<16, 256, 0, stream>>>(bo, syn_w, syn_b, bias2);
    // after all kvbuf consumers: pad out_w/out_b + write act0 into acthist[0]
    pad_act0<<<2048, 256, 0, stream>>>(out_w, out_b, start_ac, out_wp, out_bp, acthist);

    float* out_sync = out + (size_t)BB * NOUT * TT + (size_t)BB * 2 * TT;

    // ---- recurrent ticks: 3 dispatches each ----
    for (int t = 0; t < TT; ++t) {
        int par = t & 1;
        const float* act_t = acthist + (size_t)t * (BB * DD);
        float* act_n = acthist + (size_t)(t + 1) * (BB * DD);
        k1_front<<<256, 256, 0, stream>>>(act_t, idx_la, idx_ra, r_a,
                                          a_a + par * (BB * 512), b_a + par * (BB * 512),
                                          a_a + (par ^ 1) * (BB * 512), b_a + (par ^ 1) * (BB * 512),
                                          Wqq, bqq, khT, vhb, obuf);
        k2_syn<<<512, 256, 0, stream>>>(obuf, act_t, W2, syn_w, upart);
        k34_glunlm<<<256, 256, 0, stream>>>(upart, bias2, ln_syn_g, ln_syn_b, trace,
                                            nlm_w1, nlm_b1, nlm_w2, nlm_b2, act_n, t);
    }

    // ---- deferred output path ----
    k_syncscan<<<64, 256, 0, stream>>>(acthist, idx_lo, idx_ro, r_o, a_o, b_o,
                                       so_hist, out_sync);
    gemm64<0, 0><<<dim3(25, 16), 256, 0, stream>>>(so_hist, out_wp, out_bp, predt,
                                                   1600, 1024, 512);
    k6_cert<<<1600, 256, 0, stream>>>(predt, out);
}